// Round 1
// baseline (87.347 us; speedup 1.0000x reference)
//
#include <hip/hip_runtime.h>

// MultiBodyConvolution: out[n,a,:] = sum_b silu_mlp(rbfs[n,a,b,:]) * cross(r[n,a,b,:], f_old[n,a,:])
// N=64, A=256, B=128, NRBF=32, HID=32

#define NRBF 32
#define HID  32
#define BNEI 128   // neighbors per (n,a) == block size

__global__ __launch_bounds__(BNEI) void mbconv_kernel(
    const float* __restrict__ r,      // [N,A,B,3]
    const float* __restrict__ rbfs,   // [N,A,B,NRBF]
    const float* __restrict__ f_old,  // [N,A,3]
    const float* __restrict__ W1,     // [NRBF,HID]
    const float* __restrict__ b1,     // [HID]
    const float* __restrict__ W2,     // [HID]
    const float* __restrict__ b2,     // [1]
    float* __restrict__ out)          // [N,A,3]
{
    const int g = blockIdx.x;                 // n*A + a
    const int t = threadIdx.x;                // neighbor index b
    const long p = (long)g * BNEI + t;        // flat position

    // ---- load this thread's rbf row: 32 floats = 8 x float4 (one 128B line) ----
    float rbf[NRBF];
    const float4* rb4 = reinterpret_cast<const float4*>(rbfs + p * NRBF);
    #pragma unroll
    for (int i = 0; i < NRBF / 4; ++i) {
        float4 v = rb4[i];
        rbf[4*i+0] = v.x; rbf[4*i+1] = v.y; rbf[4*i+2] = v.z; rbf[4*i+3] = v.w;
    }

    // ---- hidden layer: h = rbf @ W1 + b1 (W1/b1 wave-uniform -> scalar loads) ----
    float h[HID];
    #pragma unroll
    for (int j = 0; j < HID; ++j) h[j] = b1[j];
    #pragma unroll
    for (int k = 0; k < NRBF; ++k) {
        const float rk = rbf[k];
        #pragma unroll
        for (int j = 0; j < HID; ++j)
            h[j] = fmaf(rk, W1[k * HID + j], h[j]);
    }

    // ---- gate: s = silu(h) @ W2 + b2 ----
    float s = b2[0];
    #pragma unroll
    for (int j = 0; j < HID; ++j) {
        const float x   = h[j];
        const float sig = 1.0f / (1.0f + __expf(-x));  // v_exp_f32 fast path
        s = fmaf(x * sig, W2[j], s);
    }

    // ---- cross(r, f_old) * s ----
    const float r0 = r[p*3+0], r1 = r[p*3+1], r2 = r[p*3+2];
    const float f0 = f_old[g*3+0], f1 = f_old[g*3+1], f2 = f_old[g*3+2]; // wave-uniform
    float cx = (r1*f2 - r2*f1) * s;
    float cy = (r2*f0 - r0*f2) * s;
    float cz = (r0*f1 - r1*f0) * s;

    // ---- reduce over 128 neighbors: wave shuffle then 2-wave LDS combine ----
    #pragma unroll
    for (int off = 32; off > 0; off >>= 1) {
        cx += __shfl_down(cx, off);
        cy += __shfl_down(cy, off);
        cz += __shfl_down(cz, off);
    }
    __shared__ float red[2][3];
    const int wave = t >> 6;
    if ((t & 63) == 0) {
        red[wave][0] = cx; red[wave][1] = cy; red[wave][2] = cz;
    }
    __syncthreads();
    if (t == 0) {
        out[(long)g*3 + 0] = red[0][0] + red[1][0];
        out[(long)g*3 + 1] = red[0][1] + red[1][1];
        out[(long)g*3 + 2] = red[0][2] + red[1][2];
    }
}

extern "C" void kernel_launch(void* const* d_in, const int* in_sizes, int n_in,
                              void* d_out, int out_size, void* d_ws, size_t ws_size,
                              hipStream_t stream) {
    // inputs: 0=t (unused), 1=r, 2=rbfs, 3=f_old, 4=W1, 5=b1, 6=W2, 7=b2
    const float* r     = (const float*)d_in[1];
    const float* rbfs  = (const float*)d_in[2];
    const float* f_old = (const float*)d_in[3];
    const float* W1    = (const float*)d_in[4];
    const float* b1    = (const float*)d_in[5];
    const float* W2    = (const float*)d_in[6];
    const float* b2    = (const float*)d_in[7];
    float* out = (float*)d_out;

    const int NA = in_sizes[3] / 3;   // N*A = 16384 blocks, one per (n,a)
    mbconv_kernel<<<NA, BNEI, 0, stream>>>(r, rbfs, f_old, W1, b1, W2, b2, out);
}

// Round 2
// 53.824 us; speedup vs baseline: 1.6228x; 1.6228x over previous
//
#include <hip/hip_runtime.h>

// MultiBodyConvolution via MFMA:
//   h^T[hid][pos] = W1^T @ rbf^T  (mfma_f32_16x16x32_bf16, K=NRBF=32, hi/lo split)
//   s[pos] = silu(h+b1) @ W2 + b2 ; out[n,a,:] = sum_b s * cross(r, f_old)
// N=64, A=256, B=128, NRBF=32, HID=32

#define NRBF 32
#define HID  32

typedef __attribute__((ext_vector_type(8))) short bf16x8;   // 8 bf16 (4 VGPRs)
typedef __attribute__((ext_vector_type(4))) float f32x4;

// split fp32 into bf16 hi (bit-truncate) + bf16 lo (residual); hi+lo ~ 2^-16 rel err
__device__ __forceinline__ void split_bf16(float x, short& hi, short& lo) {
    unsigned u  = __builtin_bit_cast(unsigned, x);
    unsigned hu = u & 0xFFFF0000u;
    hi = (short)(hu >> 16);
    float l = x - __builtin_bit_cast(float, hu);
    lo = (short)(__builtin_bit_cast(unsigned, l) >> 16);
}

__global__ __launch_bounds__(256) void mbconv_mfma(
    const float* __restrict__ r,      // [N,A,B,3]
    const float* __restrict__ rbfs,   // [N,A,B,NRBF]
    const float* __restrict__ f_old,  // [N,A,3]
    const float* __restrict__ W1,     // [NRBF,HID]
    const float* __restrict__ b1,     // [HID]
    const float* __restrict__ W2,     // [HID]
    const float* __restrict__ b2,     // [1]
    float* __restrict__ out)          // [N,A,3]
{
    const int t    = threadIdx.x;
    const int wave = t >> 6;
    const int l    = t & 63;
    const int lo4  = l & 15;      // D col = position-in-tile ; A row = hid-in-tile
    const int hi2  = l >> 4;      // k-group for A/B fragments ; D row-group

    const int  grp    = (blockIdx.x << 1) | (wave >> 1);  // n*A + a
    const int  nb     = (wave & 1) << 6;                  // neighbor base (0 / 64)
    const long p_base = (long)grp * 128 + nb;             // first flat position of this wave

    // ---- issue rbf B-fragment loads early: 4 pos-tiles x 2 float4/lane ----
    const float4* rb4 = reinterpret_cast<const float4*>(rbfs);
    float4 stg[8];
    #pragma unroll
    for (int T = 0; T < 4; ++T) {
        const long row = (p_base + T * 16 + lo4) * (NRBF / 4) + hi2 * 2; // float4 units
        stg[2 * T + 0] = rb4[row];
        stg[2 * T + 1] = rb4[row + 1];
    }

    // ---- r for the owned position (pos = p_base + l) ----
    const long pr = (p_base + l) * 3;
    const float r0 = r[pr + 0], r1 = r[pr + 1], r2 = r[pr + 2];

    // ---- A fragments: W1^T tiles (hid 0-15 / 16-31), loaded once, hi/lo split ----
    bf16x8 a_hi[2], a_lo[2];
    #pragma unroll
    for (int H = 0; H < 2; ++H) {
        #pragma unroll
        for (int e = 0; e < 8; ++e) {
            const float w = W1[(hi2 * 8 + e) * HID + H * 16 + lo4];
            short h, lw; split_bf16(w, h, lw);
            a_hi[H][e] = h; a_lo[H][e] = lw;
        }
    }

    // ---- per-lane bias / W2 slices: hid = H*16 + hi2*4 + q ----
    const float4 b1v0 = *reinterpret_cast<const float4*>(b1 + hi2 * 4);
    const float4 b1v1 = *reinterpret_cast<const float4*>(b1 + 16 + hi2 * 4);
    const float4 w2v0 = *reinterpret_cast<const float4*>(W2 + hi2 * 4);
    const float4 w2v1 = *reinterpret_cast<const float4*>(W2 + 16 + hi2 * 4);
    const float b2v = b2[0];
    const float f0 = f_old[grp * 3 + 0], f1 = f_old[grp * 3 + 1], f2 = f_old[grp * 3 + 2];

    // ---- MFMA: D[hid][pos] per (pos-tile T, hid-tile H); 3 combos (skip lo*lo) ----
    f32x4 acc[4][2];
    #pragma unroll
    for (int T = 0; T < 4; ++T)
        #pragma unroll
        for (int H = 0; H < 2; ++H)
            acc[T][H] = f32x4{0.f, 0.f, 0.f, 0.f};

    #pragma unroll
    for (int T = 0; T < 4; ++T) {
        const float xv[8] = { stg[2*T].x, stg[2*T].y, stg[2*T].z, stg[2*T].w,
                              stg[2*T+1].x, stg[2*T+1].y, stg[2*T+1].z, stg[2*T+1].w };
        bf16x8 bhi, blo;
        #pragma unroll
        for (int e = 0; e < 8; ++e) {
            short h, lw; split_bf16(xv[e], h, lw);
            bhi[e] = h; blo[e] = lw;
        }
        #pragma unroll
        for (int H = 0; H < 2; ++H) {
            acc[T][H] = __builtin_amdgcn_mfma_f32_16x16x32_bf16(a_hi[H], bhi, acc[T][H], 0, 0, 0);
            acc[T][H] = __builtin_amdgcn_mfma_f32_16x16x32_bf16(a_hi[H], blo, acc[T][H], 0, 0, 0);
            acc[T][H] = __builtin_amdgcn_mfma_f32_16x16x32_bf16(a_lo[H], bhi, acc[T][H], 0, 0, 0);
        }
    }

    // ---- gate: s[pos] = silu(h + b1) @ W2 + b2 ; reduce over hid (lanes l^16, l^32) ----
    float s0, s1, s2, s3;
    #pragma unroll
    for (int T = 0; T < 4; ++T) {
        float ps = 0.f;
        #pragma unroll
        for (int H = 0; H < 2; ++H) {
            const float4 b1v = H ? b1v1 : b1v0;
            const float4 w2v = H ? w2v1 : w2v0;
            #pragma unroll
            for (int q = 0; q < 4; ++q) {
                const float h  = acc[T][H][q] + ((const float*)&b1v)[q];
                const float ex = __expf(-h);
                const float sl = h * __builtin_amdgcn_rcpf(1.f + ex);
                ps = fmaf(sl, ((const float*)&w2v)[q], ps);
            }
        }
        ps += __shfl_xor(ps, 16);
        ps += __shfl_xor(ps, 32);
        ps += b2v;
        if (T == 0) s0 = ps; else if (T == 1) s1 = ps; else if (T == 2) s2 = ps; else s3 = ps;
    }
    // lane l owns pos p_base + l = (hi2)*16 + lo4 -> pick tile by hi2 (cndmask chain)
    const float s_own = hi2 == 0 ? s0 : hi2 == 1 ? s1 : hi2 == 2 ? s2 : s3;

    // ---- cross(r, f_old) * s, reduce over 64 neighbors in-wave ----
    float cx = (r1 * f2 - r2 * f1) * s_own;
    float cy = (r2 * f0 - r0 * f2) * s_own;
    float cz = (r0 * f1 - r1 * f0) * s_own;
    #pragma unroll
    for (int off = 32; off > 0; off >>= 1) {
        cx += __shfl_down(cx, off);
        cy += __shfl_down(cy, off);
        cz += __shfl_down(cz, off);
    }

    // ---- combine the 2 waves of each group, write out ----
    __shared__ float red[4][3];
    if (l == 0) { red[wave][0] = cx; red[wave][1] = cy; red[wave][2] = cz; }
    __syncthreads();
    if (t < 2) {
        const long g = ((long)blockIdx.x << 1) | t;
        out[g * 3 + 0] = red[2 * t][0] + red[2 * t + 1][0];
        out[g * 3 + 1] = red[2 * t][1] + red[2 * t + 1][1];
        out[g * 3 + 2] = red[2 * t][2] + red[2 * t + 1][2];
    }
}

extern "C" void kernel_launch(void* const* d_in, const int* in_sizes, int n_in,
                              void* d_out, int out_size, void* d_ws, size_t ws_size,
                              hipStream_t stream) {
    // inputs: 0=t (unused), 1=r, 2=rbfs, 3=f_old, 4=W1, 5=b1, 6=W2, 7=b2
    const float* r     = (const float*)d_in[1];
    const float* rbfs  = (const float*)d_in[2];
    const float* f_old = (const float*)d_in[3];
    const float* W1    = (const float*)d_in[4];
    const float* b1    = (const float*)d_in[5];
    const float* W2    = (const float*)d_in[6];
    const float* b2    = (const float*)d_in[7];
    float* out = (float*)d_out;

    const int NA = in_sizes[3] / 3;        // 16384 (n,a) groups
    const int blocks = NA / 2;             // 2 groups (256 positions) per block
    mbconv_mfma<<<blocks, 256, 0, stream>>>(r, rbfs, f_old, W1, b1, W2, b2, out);
}

// Round 3
// 50.844 us; speedup vs baseline: 1.7179x; 1.0586x over previous
//
#include <hip/hip_runtime.h>

// MultiBodyConvolution via MFMA:
//   h^T[hid][pos] = W1^T @ rbf^T  (mfma_f32_16x16x32_bf16, K=NRBF=32, hi/lo split)
//   s[pos] = silu(h+b1) @ W2 + b2 ; out[n,a,:] = sum_b s * cross(r, f_old)
// N=64, A=256, B=128, NRBF=32, HID=32
//
// R3: register-pressure round. Per-tile epilogue (acc[T] consumed right after
// its MFMAs), launch_bounds(256,4) to pin <=128 VGPR (16 waves/CU), scalarized
// f_old via readfirstlane. Algorithm identical to R2.

#define NRBF 32
#define HID  32

typedef __attribute__((ext_vector_type(8))) short bf16x8;   // 8 bf16 (4 VGPRs)
typedef __attribute__((ext_vector_type(4))) float f32x4;

// split fp32 into bf16 hi (bit-truncate) + bf16 lo (residual); hi+lo ~ 2^-16 rel err
__device__ __forceinline__ void split_bf16(float x, short& hi, short& lo) {
    unsigned u  = __builtin_bit_cast(unsigned, x);
    unsigned hu = u & 0xFFFF0000u;
    hi = (short)(hu >> 16);
    float l = x - __builtin_bit_cast(float, hu);
    lo = (short)(__builtin_bit_cast(unsigned, l) >> 16);
}

__global__ __launch_bounds__(256, 4) void mbconv_mfma(
    const float* __restrict__ r,      // [N,A,B,3]
    const float* __restrict__ rbfs,   // [N,A,B,NRBF]
    const float* __restrict__ f_old,  // [N,A,3]
    const float* __restrict__ W1,     // [NRBF,HID]
    const float* __restrict__ b1,     // [HID]
    const float* __restrict__ W2,     // [HID]
    const float* __restrict__ b2,     // [1]
    float* __restrict__ out)          // [N,A,3]
{
    const int t    = threadIdx.x;
    const int wave = t >> 6;
    const int l    = t & 63;
    const int lo4  = l & 15;      // D col = position-in-tile ; A row = hid-in-tile
    const int hi2  = l >> 4;      // k-group for A/B fragments ; D row-group

    // wave-uniform group index -> SGPR (scalar loads for f_old)
    const int  grp    = __builtin_amdgcn_readfirstlane((blockIdx.x << 1) | (wave >> 1));
    const int  nb     = (wave & 1) << 6;                  // neighbor base (0 / 64)
    const long p_base = (long)grp * 128 + nb;             // first flat position of this wave

    // ---- issue ALL global loads up front: 8x float4 rbf + 3x dword r ----
    const float4* rb4 = reinterpret_cast<const float4*>(rbfs);
    float4 stg[8];
    #pragma unroll
    for (int T = 0; T < 4; ++T) {
        const long row = (p_base + T * 16 + lo4) * (NRBF / 4) + hi2 * 2; // float4 units
        stg[2 * T + 0] = rb4[row];
        stg[2 * T + 1] = rb4[row + 1];
    }
    const long pr = (p_base + l) * 3;
    const float r0 = r[pr + 0], r1 = r[pr + 1], r2 = r[pr + 2];
    const float f0 = f_old[grp * 3 + 0], f1 = f_old[grp * 3 + 1], f2 = f_old[grp * 3 + 2]; // s_load

    // ---- A fragments: W1^T tiles (hid 0-15 / 16-31), loaded once, hi/lo split ----
    bf16x8 a_hi[2], a_lo[2];
    #pragma unroll
    for (int H = 0; H < 2; ++H) {
        #pragma unroll
        for (int e = 0; e < 8; ++e) {
            const float w = W1[(hi2 * 8 + e) * HID + H * 16 + lo4];
            short h, lw; split_bf16(w, h, lw);
            a_hi[H][e] = h; a_lo[H][e] = lw;
        }
    }

    // ---- per-lane bias / W2 slices: hid = H*16 + hi2*4 + q ----
    const float4 b1v0 = *reinterpret_cast<const float4*>(b1 + hi2 * 4);
    const float4 b1v1 = *reinterpret_cast<const float4*>(b1 + 16 + hi2 * 4);
    const float4 w2v0 = *reinterpret_cast<const float4*>(W2 + hi2 * 4);
    const float4 w2v1 = *reinterpret_cast<const float4*>(W2 + 16 + hi2 * 4);
    const float b2v = b2[0];

    // ---- per pos-tile: split -> 3x2 MFMA -> silu/gate epilogue (acc freed per tile) ----
    float s_arr[4];
    #pragma unroll
    for (int T = 0; T < 4; ++T) {
        const float xv[8] = { stg[2*T].x, stg[2*T].y, stg[2*T].z, stg[2*T].w,
                              stg[2*T+1].x, stg[2*T+1].y, stg[2*T+1].z, stg[2*T+1].w };
        bf16x8 bhi, blo;
        #pragma unroll
        for (int e = 0; e < 8; ++e) {
            short h, lw; split_bf16(xv[e], h, lw);
            bhi[e] = h; blo[e] = lw;
        }
        float ps = 0.f;
        #pragma unroll
        for (int H = 0; H < 2; ++H) {
            f32x4 acc = f32x4{0.f, 0.f, 0.f, 0.f};
            acc = __builtin_amdgcn_mfma_f32_16x16x32_bf16(a_hi[H], bhi, acc, 0, 0, 0);
            acc = __builtin_amdgcn_mfma_f32_16x16x32_bf16(a_hi[H], blo, acc, 0, 0, 0);
            acc = __builtin_amdgcn_mfma_f32_16x16x32_bf16(a_lo[H], bhi, acc, 0, 0, 0);
            const float4 b1v = H ? b1v1 : b1v0;
            const float4 w2v = H ? w2v1 : w2v0;
            #pragma unroll
            for (int q = 0; q < 4; ++q) {
                const float h  = acc[q] + ((const float*)&b1v)[q];
                const float ex = __expf(-h);
                const float sl = h * __builtin_amdgcn_rcpf(1.f + ex);
                ps = fmaf(sl, ((const float*)&w2v)[q], ps);
            }
        }
        ps += __shfl_xor(ps, 16);
        ps += __shfl_xor(ps, 32);
        s_arr[T] = ps + b2v;
    }
    // lane l owns pos p_base + l = hi2*16 + lo4 -> pick its tile's s by hi2
    const float s_own = hi2 == 0 ? s_arr[0] : hi2 == 1 ? s_arr[1] : hi2 == 2 ? s_arr[2] : s_arr[3];

    // ---- cross(r, f_old) * s, reduce over 64 neighbors in-wave ----
    float cx = (r1 * f2 - r2 * f1) * s_own;
    float cy = (r2 * f0 - r0 * f2) * s_own;
    float cz = (r0 * f1 - r1 * f0) * s_own;
    #pragma unroll
    for (int off = 32; off > 0; off >>= 1) {
        cx += __shfl_down(cx, off);
        cy += __shfl_down(cy, off);
        cz += __shfl_down(cz, off);
    }

    // ---- combine the 2 waves of each group, write out ----
    __shared__ float red[4][3];
    if (l == 0) { red[wave][0] = cx; red[wave][1] = cy; red[wave][2] = cz; }
    __syncthreads();
    if (t < 2) {
        const long g = ((long)blockIdx.x << 1) | t;
        out[g * 3 + 0] = red[2 * t][0] + red[2 * t + 1][0];
        out[g * 3 + 1] = red[2 * t][1] + red[2 * t + 1][1];
        out[g * 3 + 2] = red[2 * t][2] + red[2 * t + 1][2];
    }
}

extern "C" void kernel_launch(void* const* d_in, const int* in_sizes, int n_in,
                              void* d_out, int out_size, void* d_ws, size_t ws_size,
                              hipStream_t stream) {
    // inputs: 0=t (unused), 1=r, 2=rbfs, 3=f_old, 4=W1, 5=b1, 6=W2, 7=b2
    const float* r     = (const float*)d_in[1];
    const float* rbfs  = (const float*)d_in[2];
    const float* f_old = (const float*)d_in[3];
    const float* W1    = (const float*)d_in[4];
    const float* b1    = (const float*)d_in[5];
    const float* W2    = (const float*)d_in[6];
    const float* b2    = (const float*)d_in[7];
    float* out = (float*)d_out;

    const int NA = in_sizes[3] / 3;        // 16384 (n,a) groups
    const int blocks = NA / 2;             // 2 groups (256 positions) per block
    mbconv_mfma<<<blocks, 256, 0, stream>>>(r, rbfs, f_old, W1, b1, W2, b2, out);
}